// Round 13
// baseline (169.639 us; speedup 1.0000x reference)
//
#include <hip/hip_runtime.h>
#include <hip/hip_bf16.h>
#include <math.h>

typedef __bf16 bf16;
typedef __bf16 bf16x8 __attribute__((ext_vector_type(8)));
typedef __bf16 bf16x4 __attribute__((ext_vector_type(4)));
typedef float  f32x4  __attribute__((ext_vector_type(4)));
typedef float  f32x16 __attribute__((ext_vector_type(16)));
typedef _Float16 f16x8 __attribute__((ext_vector_type(8)));

#define MFMA(a, b, c)   __builtin_amdgcn_mfma_f32_16x16x32_bf16((a), (b), (c), 0, 0, 0)
#define MFMA32(a, b, c) __builtin_amdgcn_mfma_f32_32x32x16_bf16((a), (b), (c), 0, 0, 0)
#define LOG2E 1.4426950408889634f

union U8 { unsigned u[4]; bf16x8 v; };

// ---------------------------------------------------------------------------
// Kernel P: fused prep.  grid 8769:
//   block 0        : pos MLP (961 rows, 2->12->12->12->6) -> lane-permuted
//                    pos32g bf16 table (per-head LDS bounce, 3.8 KB)
//   blocks 1..576  : precast w_qkv^T -> wqT, w_proj^T -> wpT (bf16)
//   blocks 577..   : lane-permuted f16 mask table maskp (*log2e)
// ---------------------------------------------------------------------------
__global__ __launch_bounds__(256) void megaprep_kernel(
    const float* __restrict__ w_qkv, const float* __restrict__ w_proj,
    const float* __restrict__ mask,
    const float* __restrict__ pw0, const float* __restrict__ pb0,
    const float* __restrict__ g1,  const float* __restrict__ be1,
    const float* __restrict__ w1,  const float* __restrict__ b1,
    const float* __restrict__ g2,  const float* __restrict__ be2,
    const float* __restrict__ w2,  const float* __restrict__ b2,
    const float* __restrict__ g3,  const float* __restrict__ be3,
    const float* __restrict__ w3,  const float* __restrict__ b3,
    bf16* __restrict__ wqT, bf16* __restrict__ wpT,
    bf16* __restrict__ pos32g, _Float16* __restrict__ maskp) {
  __shared__ float posh[961];
  const int blk = blockIdx.x;
  const int t = threadIdx.x;

  if (blk == 0) {
    // ---- pos MLP: thread t owns rows t, t+256, t+512, t+768 ----
    float outv[4][6];
    const float* G[3]  = {g1, g2, g3};
    const float* BE[3] = {be1, be2, be3};
    const float* W[3]  = {w1, w2, w3};
    const float* BB[3] = {b1, b2, b3};
#pragma unroll
    for (int k = 0; k < 4; k++) {
      int i = t + k * 256;
      if (i >= 961) break;
      float bh = (float)(i / 31) - 15.0f;
      float bw = (float)(i % 31) - 15.0f;
      float xv[12];
#pragma unroll
      for (int j = 0; j < 12; j++) xv[j] = bh * pw0[j] + bw * pw0[12 + j] + pb0[j];
#pragma unroll
      for (int s = 0; s < 3; s++) {
        float m = 0.f;
#pragma unroll
        for (int j = 0; j < 12; j++) m += xv[j];
        m *= (1.0f / 12.0f);
        float v = 0.f;
#pragma unroll
        for (int j = 0; j < 12; j++) { float d = xv[j] - m; v += d * d; }
        v *= (1.0f / 12.0f);
        float inv = 1.0f / sqrtf(v + 1e-5f);
        float y[12];
#pragma unroll
        for (int j = 0; j < 12; j++) {
          float tt = (xv[j] - m) * inv * G[s][j] + BE[s][j];
          y[j] = tt > 0.f ? tt : 0.f;
        }
        int oc = (s == 2) ? 6 : 12;
        float on[12];
        for (int c = 0; c < oc; c++) {
          float acc = BB[s][c];
#pragma unroll
          for (int j = 0; j < 12; j++) acc += y[j] * W[s][j * oc + c];
          on[c] = acc;
        }
        for (int c = 0; c < 12; c++) xv[c] = (c < oc) ? on[c] : 0.f;
      }
#pragma unroll
      for (int hh = 0; hh < 6; hh++) outv[k][hh] = xv[hh];
    }
    // ---- per head: bounce through LDS, write lane-permuted table ----
    for (int h = 0; h < 6; h++) {
      __syncthreads();
#pragma unroll
      for (int k = 0; k < 4; k++) {
        int i = t + k * 256;
        if (i < 961) posh[i] = outv[k][h];
      }
      __syncthreads();
      // pos32g[h*15872 + e], e = rd*512 + L*8 + j
      for (int e = t; e < 15872; e += 256) {
        int rd = e >> 9, idx2 = e & 511;
        int L = idx2 >> 3, j = idx2 & 7;
        int index = rd * 31 + (L & 15) - ((j & 3) + 8 * (j >> 2) + 4 * (L >> 5)) + 15;
        pos32g[h * 15872 + e] = (bf16)(posh[index] * LOG2E);
      }
    }
  } else if (blk <= 576) {
    // ---- precast: idx in [0, 147456) covers wqT (110592) then wpT (36864) ----
    int idx = (blk - 1) * 256 + t;
    if (idx < 576 * 192) {
      int c = idx / 192, k = idx % 192;
      wqT[idx] = (bf16)w_qkv[k * 576 + c];
    } else {
      int i2 = idx - 576 * 192;
      int c = i2 / 192, k = i2 % 192;
      wpT[i2] = (bf16)w_proj[k * 192 + c];
    }
  } else {
    // ---- maskprep (as R10): 2 elems per thread ----
    size_t e = ((size_t)(blk - 577) * 256 + t) * 2;
    int j  = (int)(e & 15);
    int L  = (int)((e >> 4) & 63);
    int mt = (int)((e >> 10) & 7);
    int qt = (int)((e >> 13) & 7);
    int s  = (int)(e >> 16);
    int q  = qt * 32 + (L & 31);
    int m  = mt * 32 + 16 * (j >> 3) + 8 * ((j >> 2) & 1) + 4 * (L >> 5) + (j & 3);
    const float* src = mask + ((size_t)s * 256 + q) * 256 + m;
    maskp[e]     = (_Float16)(src[0] * LOG2E);
    maskp[e + 1] = (_Float16)(src[1] * LOG2E);
  }
}

// ---------------------------------------------------------------------------
// Kernel B: QKV GEMM (unchanged, proven).  grid 512, BM=128, rt=2.
// ---------------------------------------------------------------------------
#define SMEM_G (192 * 200 * 2)

__global__ __launch_bounds__(256) void qkv_gemm_kernel(
    const float* __restrict__ x, const bf16* __restrict__ wqT,
    const float* __restrict__ b_qkv, bf16* __restrict__ qw,
    bf16* __restrict__ kw, bf16* __restrict__ vwT) {
  extern __shared__ char smem[];
  bf16* wt = (bf16*)smem;   // [192 c][200 k]
  const int tid = threadIdx.x;
  const int lane = tid & 63, w = tid >> 6;
  const int cI = lane & 15, gI = lane >> 4;
  const int row0 = blockIdx.x * 128 + w * 32;
  const int b = blockIdx.x >> 1;
  const float QSCALE = 0.17677669529663687f * LOG2E;

  bf16x8 afr[2][6];
#pragma unroll
  for (int rt = 0; rt < 2; rt++) {
#pragma unroll
    for (int kk = 0; kk < 6; kk++) {
      const float* p = x + (size_t)(row0 + rt * 16 + cI) * 192 + kk * 32 + gI * 8;
      float4 f0 = *(const float4*)p;
      float4 f1 = *(const float4*)(p + 4);
      bf16x8 a;
      a[0] = (bf16)f0.x; a[1] = (bf16)f0.y; a[2] = (bf16)f0.z; a[3] = (bf16)f0.w;
      a[4] = (bf16)f1.x; a[5] = (bf16)f1.y; a[6] = (bf16)f1.z; a[7] = (bf16)f1.w;
      afr[rt][kk] = a;
    }
  }

#pragma unroll
  for (int mat = 0; mat < 3; mat++) {
    __syncthreads();
#pragma unroll
    for (int it = 0; it < 18; it++) {
      int idx = it * 256 + tid;
      int c = idx / 24, ch = idx % 24;
      bf16x8 v8 = *(const bf16x8*)(wqT + (size_t)(mat * 192 + c) * 192 + ch * 8);
      *(bf16x8*)(wt + c * 200 + ch * 8) = v8;
    }
    __syncthreads();
#pragma unroll
    for (int ct = 0; ct < 12; ct++) {
      bf16x8 wfr[6];
#pragma unroll
      for (int kk = 0; kk < 6; kk++)
        wfr[kk] = *(const bf16x8*)(wt + (ct * 16 + cI) * 200 + kk * 32 + gI * 8);
      if (mat < 2) {
        f32x4 bv4 = *(const f32x4*)(b_qkv + mat * 192 + ct * 16 + gI * 4);
        bf16* dst = (mat == 0) ? qw : kw;
#pragma unroll
        for (int rt = 0; rt < 2; rt++) {
          f32x4 acc = {0.f, 0.f, 0.f, 0.f};
#pragma unroll
          for (int kk = 0; kk < 6; kk++) acc = MFMA(wfr[kk], afr[rt][kk], acc);
          int n = (row0 + rt * 16 + cI) & 255;
          int c0 = ct * 16 + gI * 4;
          int h = c0 >> 5, d0 = c0 & 31;
          bf16x4 o4;
          if (mat == 0) {
#pragma unroll
            for (int r = 0; r < 4; r++) o4[r] = (bf16)((acc[r] + bv4[r]) * QSCALE);
          } else {
#pragma unroll
            for (int r = 0; r < 4; r++) o4[r] = (bf16)(acc[r] + bv4[r]);
          }
          *(bf16x4*)(dst + ((size_t)(b * 6 + h) * 256 + n) * 32 + d0) = o4;
        }
      } else {
        float bv = b_qkv[384 + ct * 16 + cI];
        int c = ct * 16 + cI, h = c >> 5, d = c & 31;
#pragma unroll
        for (int rt = 0; rt < 2; rt++) {
          f32x4 acc = {0.f, 0.f, 0.f, 0.f};
#pragma unroll
          for (int kk = 0; kk < 6; kk++) acc = MFMA(afr[rt][kk], wfr[kk], acc);
          int n0 = ((row0 + rt * 16) & 255) + gI * 4;
          bf16x4 o4;
#pragma unroll
          for (int r = 0; r < 4; r++) o4[r] = (bf16)(acc[r] + bv);
          *(bf16x4*)(vwT + ((size_t)(b * 6 + h) * 32 + d) * 256 + n0) = o4;
        }
      }
    }
  }
}

// ---------------------------------------------------------------------------
// Kernel C: flash attention — R10 structure verbatim (63 us verified), only
// launch_bounds min-waves 4 -> 3 (VGPR cap 128 -> 170; kills any spill).
// grid 1536 (b,h), 4 waves x 64 q rows = 2 subtiles of 32, K/V frags shared.
// ---------------------------------------------------------------------------
__global__ __launch_bounds__(256, 3) void attn_kernel(
    const bf16* __restrict__ qw, const bf16* __restrict__ kw,
    const bf16* __restrict__ vwT, const _Float16* __restrict__ maskp,
    const bf16* __restrict__ pos32g, bf16* __restrict__ ctx) {
  const int tid = threadIdx.x;
  const int bid = blockIdx.x;
  const int s_ = bid & 63, j_ = bid >> 6;          // mask slice; XCD = bid%8 = s_%8
  const int g_ = j_ & 3, h = j_ >> 2;
  const int b = g_ * 64 + s_;

  const bf16* qb = qw  + (size_t)(b * 6 + h) * 8192;
  const bf16* kb = kw  + (size_t)(b * 6 + h) * 8192;
  const bf16* vb = vwT + (size_t)(b * 6 + h) * 8192;
  const bf16* pg = pos32g + (size_t)h * (31 * 512);

  const int lane = tid & 63, w = tid >> 6;
  const int q5 = lane & 31, hi = lane >> 5;

  bf16x8 qf[2][2];
#pragma unroll
  for (int sub = 0; sub < 2; sub++) {
    int qa = w * 64 + sub * 32 + q5;
    qf[sub][0] = *(const bf16x8*)(qb + qa * 32 + hi * 8);
    qf[sub][1] = *(const bf16x8*)(qb + qa * 32 + 16 + hi * 8);
  }

  f32x16 o[2];
  float l[2], mr[2];
#pragma unroll
  for (int sub = 0; sub < 2; sub++) {
#pragma unroll
    for (int r = 0; r < 16; r++) o[sub][r] = 0.f;
    l[sub] = 0.f; mr[sub] = -3.0e38f;
  }

  for (int mt = 0; mt < 8; mt++) {
    const int m0 = mt * 32;
    bf16x8 kf0 = *(const bf16x8*)(kb + (m0 + q5) * 32 + hi * 8);
    bf16x8 kf1 = *(const bf16x8*)(kb + (m0 + q5) * 32 + 16 + hi * 8);
    const bf16* vrow = vb + q5 * 256 + m0 + 4 * hi;
    bf16x4 v00 = *(const bf16x4*)(vrow);
    bf16x4 v01 = *(const bf16x4*)(vrow + 8);
    bf16x4 v10 = *(const bf16x4*)(vrow + 16);
    bf16x4 v11 = *(const bf16x4*)(vrow + 24);
    bf16x8 vf0, vf1;
#pragma unroll
    for (int j2 = 0; j2 < 4; j2++) {
      vf0[j2] = v00[j2]; vf0[4 + j2] = v01[j2];
      vf1[j2] = v10[j2]; vf1[4 + j2] = v11[j2];
    }

#pragma unroll
    for (int sub = 0; sub < 2; sub++) {
      const int qa = w * 64 + sub * 32 + q5;
      const int rn = qa >> 4;
      const int rd0 = rn - 2 * mt + 15;
      bf16x8 plo = *(const bf16x8*)(pg + ((size_t)rd0 * 64 + lane) * 8);
      bf16x8 phi = *(const bf16x8*)(pg + ((size_t)(rd0 - 1) * 64 + lane) * 8);
      const _Float16* mrow =
          maskp + ((((size_t)s_ * 8 + (w * 2 + sub)) * 8 + mt) * 64 + lane) * 16;
      f16x8 mk0 = *(const f16x8*)(mrow);
      f16x8 mk1 = *(const f16x8*)(mrow + 8);

      f32x16 sa;
#pragma unroll
      for (int r = 0; r < 16; r++) sa[r] = 0.f;
      __builtin_amdgcn_s_setprio(1);
      sa = MFMA32(kf0, qf[sub][0], sa);
      sa = MFMA32(kf1, qf[sub][1], sa);
      __builtin_amdgcn_s_setprio(0);

#pragma unroll
      for (int r = 0; r < 8; r++)  sa[r]     += (float)mk0[r] + (float)plo[r];
#pragma unroll
      for (int r = 8; r < 16; r++) sa[r]     += (float)mk1[r - 8] + (float)phi[r - 8];

      float t = sa[0];
#pragma unroll
      for (int r = 1; r < 16; r++) t = fmaxf(t, sa[r]);
      t = fmaxf(t, __shfl_xor(t, 32));

      if (!__all(t - mr[sub] <= 8.0f)) {     // defer-max: rare after tile 0
        float mn = fmaxf(mr[sub], t);
        float fsc = exp2f(mr[sub] - mn);
        mr[sub] = mn;
        l[sub] *= fsc;
#pragma unroll
        for (int r = 0; r < 16; r++) {
          float f = __shfl(fsc, (r & 3) + 8 * (r >> 2) + 4 * hi);
          o[sub][r] *= f;
        }
      }

      float ls = 0.f;
#pragma unroll
      for (int r = 0; r < 16; r++) {
        float p = exp2f(sa[r] - mr[sub]);
        sa[r] = p;
        ls += p;
      }
      ls += __shfl_xor(ls, 32);
      l[sub] += ls;

      unsigned a0, a1, b0, b1, c0, c1, d0, d1;
      asm("v_cvt_pk_bf16_f32 %0, %1, %2" : "=v"(a0) : "v"(sa[0]),  "v"(sa[1]));
      asm("v_cvt_pk_bf16_f32 %0, %1, %2" : "=v"(a1) : "v"(sa[2]),  "v"(sa[3]));
      asm("v_cvt_pk_bf16_f32 %0, %1, %2" : "=v"(b0) : "v"(sa[4]),  "v"(sa[5]));
      asm("v_cvt_pk_bf16_f32 %0, %1, %2" : "=v"(b1) : "v"(sa[6]),  "v"(sa[7]));
      asm("v_cvt_pk_bf16_f32 %0, %1, %2" : "=v"(c0) : "v"(sa[8]),  "v"(sa[9]));
      asm("v_cvt_pk_bf16_f32 %0, %1, %2" : "=v"(c1) : "v"(sa[10]), "v"(sa[11]));
      asm("v_cvt_pk_bf16_f32 %0, %1, %2" : "=v"(d0) : "v"(sa[12]), "v"(sa[13]));
      asm("v_cvt_pk_bf16_f32 %0, %1, %2" : "=v"(d1) : "v"(sa[14]), "v"(sa[15]));
      U8 A1, A2;
      A1.u[0] = a0; A1.u[1] = a1; A1.u[2] = b0; A1.u[3] = b1;   // sigma m 0..15
      A2.u[0] = c0; A2.u[1] = c1; A2.u[2] = d0; A2.u[3] = d1;   // sigma m 16..31

      __builtin_amdgcn_s_setprio(1);
      o[sub] = MFMA32(A1.v, vf0, o[sub]);
      o[sub] = MFMA32(A2.v, vf1, o[sub]);
      __builtin_amdgcn_s_setprio(0);
    }
  }

#pragma unroll
  for (int sub = 0; sub < 2; sub++) {
    float linv = 1.0f / l[sub];
#pragma unroll
    for (int r = 0; r < 16; r++) {
      int q_local = (r & 3) + 8 * (r >> 2) + 4 * hi;
      float lv = __shfl(linv, q_local);
      int qa = w * 64 + sub * 32 + q_local;
      ctx[((size_t)(b << 8) + qa) * 192 + h * 32 + q5] = (bf16)(o[sub][r] * lv);
    }
  }
}

// ---------------------------------------------------------------------------
// Kernel D: out = ctx @ w_proj + b_proj, ZERO-LDS (wpT L2-broadcast).
// grid 512, rt=2, swapped orientation -> float4 stores.  No barrier.
// ---------------------------------------------------------------------------
__global__ __launch_bounds__(256) void proj_kernel(
    const bf16* __restrict__ ctx, const bf16* __restrict__ wpT,
    const float* __restrict__ b_proj, float* __restrict__ out) {
  const int tid = threadIdx.x;
  const int lane = tid & 63, w = tid >> 6;
  const int cI = lane & 15, gI = lane >> 4;
  const int row0 = blockIdx.x * 128 + w * 32;
  bf16x8 afr[2][6];
#pragma unroll
  for (int rt = 0; rt < 2; rt++) {
#pragma unroll
    for (int kk = 0; kk < 6; kk++)
      afr[rt][kk] = *(const bf16x8*)(ctx + (size_t)(row0 + rt * 16 + cI) * 192 +
                                     kk * 32 + gI * 8);
  }
#pragma unroll
  for (int ct = 0; ct < 12; ct++) {
    bf16x8 wfr[6];
#pragma unroll
    for (int kk = 0; kk < 6; kk++)
      wfr[kk] = *(const bf16x8*)(wpT + (size_t)(ct * 16 + cI) * 192 + kk * 32 + gI * 8);
    f32x4 bv4 = *(const f32x4*)(b_proj + ct * 16 + gI * 4);
#pragma unroll
    for (int rt = 0; rt < 2; rt++) {
      f32x4 acc = {0.f, 0.f, 0.f, 0.f};
#pragma unroll
      for (int kk = 0; kk < 6; kk++) acc = MFMA(wfr[kk], afr[rt][kk], acc);
      f32x4 res;
#pragma unroll
      for (int r = 0; r < 4; r++) res[r] = acc[r] + bv4[r];
      *(f32x4*)(out + (size_t)(row0 + rt * 16 + cI) * 192 + ct * 16 + gI * 4) = res;
    }
  }
}

// ---------------------------------------------------------------------------
extern "C" void kernel_launch(void* const* d_in, const int* in_sizes, int n_in,
                              void* d_out, int out_size, void* d_ws, size_t ws_size,
                              hipStream_t stream) {
  (void)in_sizes; (void)n_in; (void)out_size; (void)ws_size;
  const float* x      = (const float*)d_in[0];
  const float* mask   = (const float*)d_in[1];
  const float* w_qkv  = (const float*)d_in[2];
  const float* b_qkv  = (const float*)d_in[3];
  const float* w_proj = (const float*)d_in[4];
  const float* b_proj = (const float*)d_in[5];
  const float* pw0    = (const float*)d_in[6];
  const float* pb0    = (const float*)d_in[7];
  const float* g1     = (const float*)d_in[8];
  const float* be1    = (const float*)d_in[9];
  const float* w1     = (const float*)d_in[10];
  const float* b1     = (const float*)d_in[11];
  const float* g2     = (const float*)d_in[12];
  const float* be2    = (const float*)d_in[13];
  const float* w2     = (const float*)d_in[14];
  const float* b2     = (const float*)d_in[15];
  const float* g3     = (const float*)d_in[16];
  const float* be3    = (const float*)d_in[17];
  const float* w3     = (const float*)d_in[18];
  const float* b3     = (const float*)d_in[19];

  // ws layout (peak ~96.5 MB):
  //   wqT    @ 0         (221184)   bf16 [576][192]
  //   wpT    @ 221184    (73728)    bf16 [192][192]
  //   pos32g @ 294912    (190464)   bf16 [6][31][64][8]  (*log2e)
  //   qw     @ 485376    (25165824) bf16 [b][h][n][32]   (pre-scaled s*log2e)
  //   kw     @ 25651200  (25165824)
  //   vwT    @ 50817024  (25165824) bf16 [b][h][32][n]
  //   ctx    @ 75982848  (25165824)
  // maskp (f16 [64][8][8][64][16] = 8,388,608 B) lives in d_out (50 MB);
  // proj_kernel fully overwrites d_out afterwards.
  char* ws = (char*)d_ws;
  bf16*  wqT    = (bf16*)(ws);
  bf16*  wpT    = (bf16*)(ws + 221184);
  bf16*  pos32g = (bf16*)(ws + 294912);
  bf16*  qw     = (bf16*)(ws + 485376);
  bf16*  kw     = (bf16*)(ws + 25651200);
  bf16*  vwT    = (bf16*)(ws + 50817024);
  bf16*  ctx    = (bf16*)(ws + 75982848);
  _Float16* maskp = (_Float16*)d_out;
  float* outp   = (float*)d_out;

  hipFuncSetAttribute((const void*)qkv_gemm_kernel,
                      hipFuncAttributeMaxDynamicSharedMemorySize, SMEM_G);

  megaprep_kernel<<<dim3(8769), dim3(256), 0, stream>>>(
      w_qkv, w_proj, mask,
      pw0, pb0, g1, be1, w1, b1, g2, be2, w2, b2, g3, be3, w3, b3,
      wqT, wpT, pos32g, maskp);
  qkv_gemm_kernel<<<dim3(512), dim3(256), SMEM_G, stream>>>(
      x, wqT, b_qkv, qw, kw, vwT);
  attn_kernel<<<dim3(1536), dim3(256), 0, stream>>>(
      qw, kw, vwT, maskp, pos32g, ctx);
  proj_kernel<<<dim3(512), dim3(256), 0, stream>>>(
      ctx, wpT, b_proj, outp);
}

// Round 14
// 131.571 us; speedup vs baseline: 1.2893x; 1.2893x over previous
//
#include <hip/hip_runtime.h>
#include <hip/hip_bf16.h>
#include <math.h>

typedef __bf16 bf16;
typedef __bf16 bf16x8 __attribute__((ext_vector_type(8)));
typedef __bf16 bf16x4 __attribute__((ext_vector_type(4)));
typedef float  f32x4  __attribute__((ext_vector_type(4)));
typedef float  f32x16 __attribute__((ext_vector_type(16)));
typedef _Float16 f16x8 __attribute__((ext_vector_type(8)));

#define MFMA(a, b, c)   __builtin_amdgcn_mfma_f32_16x16x32_bf16((a), (b), (c), 0, 0, 0)
#define MFMA32(a, b, c) __builtin_amdgcn_mfma_f32_32x32x16_bf16((a), (b), (c), 0, 0, 0)
#define LOG2E 1.4426950408889634f

union U8 { unsigned u[4]; bf16x8 v; };

// ---------------------------------------------------------------------------
// Kernel P1: weights + mask prep (all blocks uniform small work).
//   blocks 0..575   : precast w_qkv^T -> wqT, w_proj^T -> wpT (bf16)
//   blocks 576..8767: lane-permuted f16 mask table maskp (*log2e)
// ---------------------------------------------------------------------------
__global__ __launch_bounds__(256) void prep_wm_kernel(
    const float* __restrict__ w_qkv, const float* __restrict__ w_proj,
    const float* __restrict__ mask,
    bf16* __restrict__ wqT, bf16* __restrict__ wpT,
    _Float16* __restrict__ maskp) {
  const int blk = blockIdx.x;
  const int t = threadIdx.x;
  if (blk < 576) {
    int idx = blk * 256 + t;
    if (idx < 576 * 192) {
      int c = idx / 192, k = idx % 192;
      wqT[idx] = (bf16)w_qkv[k * 576 + c];
    } else {
      int i2 = idx - 576 * 192;
      int c = i2 / 192, k = i2 % 192;
      wpT[i2] = (bf16)w_proj[k * 192 + c];
    }
  } else {
    size_t e = ((size_t)(blk - 576) * 256 + t) * 2;
    int j  = (int)(e & 15);
    int L  = (int)((e >> 4) & 63);
    int mt = (int)((e >> 10) & 7);
    int qt = (int)((e >> 13) & 7);
    int s  = (int)(e >> 16);
    int q  = qt * 32 + (L & 31);
    int m  = mt * 32 + 16 * (j >> 3) + 8 * ((j >> 2) & 1) + 4 * (L >> 5) + (j & 3);
    const float* src = mask + ((size_t)s * 256 + q) * 256 + m;
    maskp[e]     = (_Float16)(src[0] * LOG2E);
    maskp[e + 1] = (_Float16)(src[1] * LOG2E);
  }
}

// ---------------------------------------------------------------------------
// Kernel P2: pos MLP + lane-permuted f16 table, fully parallel.
// grid (31 rd, 6 h).  Each block computes its own 31 MLP rows
// (rows rd*31 .. rd*31+30), then writes its 512-entry permuted slice.
// ---------------------------------------------------------------------------
__global__ __launch_bounds__(256) void pos_prep_kernel(
    const float* __restrict__ pw0, const float* __restrict__ pb0,
    const float* __restrict__ g1,  const float* __restrict__ be1,
    const float* __restrict__ w1,  const float* __restrict__ b1,
    const float* __restrict__ g2,  const float* __restrict__ be2,
    const float* __restrict__ w2,  const float* __restrict__ b2,
    const float* __restrict__ g3,  const float* __restrict__ be3,
    const float* __restrict__ w3,  const float* __restrict__ b3,
    _Float16* __restrict__ pos16) {
  __shared__ float posh[31];
  const int rd = blockIdx.x, h = blockIdx.y;
  const int t = threadIdx.x;
  if (t < 31) {
    int i = rd * 31 + t;                       // <= 960 < 961
    float bh = (float)(i / 31) - 15.0f;
    float bw = (float)(i % 31) - 15.0f;
    float xv[12];
#pragma unroll
    for (int j = 0; j < 12; j++) xv[j] = bh * pw0[j] + bw * pw0[12 + j] + pb0[j];
    const float* G[3]  = {g1, g2, g3};
    const float* BE[3] = {be1, be2, be3};
    const float* W[3]  = {w1, w2, w3};
    const float* BB[3] = {b1, b2, b3};
#pragma unroll
    for (int s = 0; s < 3; s++) {
      float m = 0.f;
#pragma unroll
      for (int j = 0; j < 12; j++) m += xv[j];
      m *= (1.0f / 12.0f);
      float v = 0.f;
#pragma unroll
      for (int j = 0; j < 12; j++) { float d = xv[j] - m; v += d * d; }
      v *= (1.0f / 12.0f);
      float inv = 1.0f / sqrtf(v + 1e-5f);
      float y[12];
#pragma unroll
      for (int j = 0; j < 12; j++) {
        float tt = (xv[j] - m) * inv * G[s][j] + BE[s][j];
        y[j] = tt > 0.f ? tt : 0.f;
      }
      int oc = (s == 2) ? 6 : 12;
      float on[12];
      for (int c = 0; c < oc; c++) {
        float acc = BB[s][c];
#pragma unroll
        for (int j = 0; j < 12; j++) acc += y[j] * W[s][j * oc + c];
        on[c] = acc;
      }
      for (int c = 0; c < 12; c++) xv[c] = (c < oc) ? on[c] : 0.f;
    }
    posh[t] = xv[h];
  }
  __syncthreads();
  for (int e = t; e < 512; e += 256) {
    int L = e >> 3, j = e & 7;
    int idx = (L & 15) - ((j & 3) + 8 * (j >> 2) + 4 * (L >> 5)) + 15;  // 0..30
    pos16[((h * 31 + rd) * 64 + L) * 8 + j] = (_Float16)(posh[idx] * LOG2E);
  }
}

// ---------------------------------------------------------------------------
// Kernel B: QKV GEMM (unchanged, proven).  grid 512, BM=128, rt=2.
// ---------------------------------------------------------------------------
#define SMEM_G (192 * 200 * 2)

__global__ __launch_bounds__(256) void qkv_gemm_kernel(
    const float* __restrict__ x, const bf16* __restrict__ wqT,
    const float* __restrict__ b_qkv, bf16* __restrict__ qw,
    bf16* __restrict__ kw, bf16* __restrict__ vwT) {
  extern __shared__ char smem[];
  bf16* wt = (bf16*)smem;   // [192 c][200 k]
  const int tid = threadIdx.x;
  const int lane = tid & 63, w = tid >> 6;
  const int cI = lane & 15, gI = lane >> 4;
  const int row0 = blockIdx.x * 128 + w * 32;
  const int b = blockIdx.x >> 1;
  const float QSCALE = 0.17677669529663687f * LOG2E;

  bf16x8 afr[2][6];
#pragma unroll
  for (int rt = 0; rt < 2; rt++) {
#pragma unroll
    for (int kk = 0; kk < 6; kk++) {
      const float* p = x + (size_t)(row0 + rt * 16 + cI) * 192 + kk * 32 + gI * 8;
      float4 f0 = *(const float4*)p;
      float4 f1 = *(const float4*)(p + 4);
      bf16x8 a;
      a[0] = (bf16)f0.x; a[1] = (bf16)f0.y; a[2] = (bf16)f0.z; a[3] = (bf16)f0.w;
      a[4] = (bf16)f1.x; a[5] = (bf16)f1.y; a[6] = (bf16)f1.z; a[7] = (bf16)f1.w;
      afr[rt][kk] = a;
    }
  }

#pragma unroll
  for (int mat = 0; mat < 3; mat++) {
    __syncthreads();
#pragma unroll
    for (int it = 0; it < 18; it++) {
      int idx = it * 256 + tid;
      int c = idx / 24, ch = idx % 24;
      bf16x8 v8 = *(const bf16x8*)(wqT + (size_t)(mat * 192 + c) * 192 + ch * 8);
      *(bf16x8*)(wt + c * 200 + ch * 8) = v8;
    }
    __syncthreads();
#pragma unroll
    for (int ct = 0; ct < 12; ct++) {
      bf16x8 wfr[6];
#pragma unroll
      for (int kk = 0; kk < 6; kk++)
        wfr[kk] = *(const bf16x8*)(wt + (ct * 16 + cI) * 200 + kk * 32 + gI * 8);
      if (mat < 2) {
        f32x4 bv4 = *(const f32x4*)(b_qkv + mat * 192 + ct * 16 + gI * 4);
        bf16* dst = (mat == 0) ? qw : kw;
#pragma unroll
        for (int rt = 0; rt < 2; rt++) {
          f32x4 acc = {0.f, 0.f, 0.f, 0.f};
#pragma unroll
          for (int kk = 0; kk < 6; kk++) acc = MFMA(wfr[kk], afr[rt][kk], acc);
          int n = (row0 + rt * 16 + cI) & 255;
          int c0 = ct * 16 + gI * 4;
          int h = c0 >> 5, d0 = c0 & 31;
          bf16x4 o4;
          if (mat == 0) {
#pragma unroll
            for (int r = 0; r < 4; r++) o4[r] = (bf16)((acc[r] + bv4[r]) * QSCALE);
          } else {
#pragma unroll
            for (int r = 0; r < 4; r++) o4[r] = (bf16)(acc[r] + bv4[r]);
          }
          *(bf16x4*)(dst + ((size_t)(b * 6 + h) * 256 + n) * 32 + d0) = o4;
        }
      } else {
        float bv = b_qkv[384 + ct * 16 + cI];
        int c = ct * 16 + cI, h = c >> 5, d = c & 31;
#pragma unroll
        for (int rt = 0; rt < 2; rt++) {
          f32x4 acc = {0.f, 0.f, 0.f, 0.f};
#pragma unroll
          for (int kk = 0; kk < 6; kk++) acc = MFMA(afr[rt][kk], wfr[kk], acc);
          int n0 = ((row0 + rt * 16) & 255) + gI * 4;
          bf16x4 o4;
#pragma unroll
          for (int r = 0; r < 4; r++) o4[r] = (bf16)(acc[r] + bv);
          *(bf16x4*)(vwT + ((size_t)(b * 6 + h) * 32 + d) * 256 + n0) = o4;
        }
      }
    }
  }
}

// ---------------------------------------------------------------------------
// Kernel C: flash attention, 32x32 MFMA, zero LDS, no-max softmax.
// grid 1536 (b,h), 4 waves x 64 q rows = 2 subtiles of 32, K/V frags shared.
// Bias (f16 mask+pos, pk_add) is pre-loaded into the QK MFMA C-operand.
// P = exp2(S) directly (S in [-8,8]; o/ol division cancels the scale
// exactly).  l via ones-MFMA (ol, layout-matched -> shuffle-free epilogue).
// launch_bounds(256,3): VGPR cap 170 -> no spill (R12 lesson).
// ---------------------------------------------------------------------------
__global__ __launch_bounds__(256, 3) void attn_kernel(
    const bf16* __restrict__ qw, const bf16* __restrict__ kw,
    const bf16* __restrict__ vwT, const _Float16* __restrict__ maskp,
    const _Float16* __restrict__ pos16, bf16* __restrict__ ctx) {
  const int tid = threadIdx.x;
  const int bid = blockIdx.x;
  const int s_ = bid & 63, j_ = bid >> 6;          // mask slice; XCD = bid%8 = s_%8
  const int g_ = j_ & 3, h = j_ >> 2;
  const int b = g_ * 64 + s_;

  const bf16* qb = qw  + (size_t)(b * 6 + h) * 8192;
  const bf16* kb = kw  + (size_t)(b * 6 + h) * 8192;
  const bf16* vb = vwT + (size_t)(b * 6 + h) * 8192;
  const _Float16* pg = pos16 + (size_t)h * (31 * 512);

  const int lane = tid & 63, w = tid >> 6;
  const int q5 = lane & 31, hi = lane >> 5;

  bf16x8 qf[2][2];
#pragma unroll
  for (int sub = 0; sub < 2; sub++) {
    int qa = w * 64 + sub * 32 + q5;
    qf[sub][0] = *(const bf16x8*)(qb + qa * 32 + hi * 8);
    qf[sub][1] = *(const bf16x8*)(qb + qa * 32 + 16 + hi * 8);
  }

  bf16x8 ones8;
#pragma unroll
  for (int j = 0; j < 8; j++) ones8[j] = (bf16)1.0f;

  f32x16 o[2], ol[2];
#pragma unroll
  for (int sub = 0; sub < 2; sub++) {
#pragma unroll
    for (int r = 0; r < 16; r++) { o[sub][r] = 0.f; ol[sub][r] = 0.f; }
  }

  for (int mt = 0; mt < 8; mt++) {
    const int m0 = mt * 32;
    // K A-frag + V B-frag (sigma-permuted): shared across both q-subtiles
    bf16x8 kf0 = *(const bf16x8*)(kb + (m0 + q5) * 32 + hi * 8);
    bf16x8 kf1 = *(const bf16x8*)(kb + (m0 + q5) * 32 + 16 + hi * 8);
    const bf16* vrow = vb + q5 * 256 + m0 + 4 * hi;
    bf16x4 v00 = *(const bf16x4*)(vrow);
    bf16x4 v01 = *(const bf16x4*)(vrow + 8);
    bf16x4 v10 = *(const bf16x4*)(vrow + 16);
    bf16x4 v11 = *(const bf16x4*)(vrow + 24);
    bf16x8 vf0, vf1;
#pragma unroll
    for (int j2 = 0; j2 < 4; j2++) {
      vf0[j2] = v00[j2]; vf0[4 + j2] = v01[j2];
      vf1[j2] = v10[j2]; vf1[4 + j2] = v11[j2];
    }

#pragma unroll
    for (int sub = 0; sub < 2; sub++) {
      const int qa = w * 64 + sub * 32 + q5;
      const int rn = qa >> 4;
      const int rd0 = rn - 2 * mt + 15;
      f16x8 plo = *(const f16x8*)(pg + ((size_t)rd0 * 64 + lane) * 8);
      f16x8 phi = *(const f16x8*)(pg + ((size_t)(rd0 - 1) * 64 + lane) * 8);
      const _Float16* mrow =
          maskp + ((((size_t)s_ * 8 + (w * 2 + sub)) * 8 + mt) * 64 + lane) * 16;
      f16x8 mk0 = *(const f16x8*)(mrow);
      f16x8 mk1 = *(const f16x8*)(mrow + 8);
      // bias = mask + pos in packed f16, then init the MFMA accumulator
      f16x8 b0v = mk0 + plo;
      f16x8 b1v = mk1 + phi;
      f32x16 sa;
#pragma unroll
      for (int r = 0; r < 8; r++)  sa[r]     = (float)b0v[r];
#pragma unroll
      for (int r = 0; r < 8; r++)  sa[8 + r] = (float)b1v[r];

      __builtin_amdgcn_s_setprio(1);
      sa = MFMA32(kf0, qf[sub][0], sa);
      sa = MFMA32(kf1, qf[sub][1], sa);
      __builtin_amdgcn_s_setprio(0);

      // P = 2^sa directly (no max machinery; division cancels scale)
#pragma unroll
      for (int r = 0; r < 16; r++) sa[r] = exp2f(sa[r]);

      unsigned a0, a1, b0, b1, c0, c1, d0, d1;
      asm("v_cvt_pk_bf16_f32 %0, %1, %2" : "=v"(a0) : "v"(sa[0]),  "v"(sa[1]));
      asm("v_cvt_pk_bf16_f32 %0, %1, %2" : "=v"(a1) : "v"(sa[2]),  "v"(sa[3]));
      asm("v_cvt_pk_bf16_f32 %0, %1, %2" : "=v"(b0) : "v"(sa[4]),  "v"(sa[5]));
      asm("v_cvt_pk_bf16_f32 %0, %1, %2" : "=v"(b1) : "v"(sa[6]),  "v"(sa[7]));
      asm("v_cvt_pk_bf16_f32 %0, %1, %2" : "=v"(c0) : "v"(sa[8]),  "v"(sa[9]));
      asm("v_cvt_pk_bf16_f32 %0, %1, %2" : "=v"(c1) : "v"(sa[10]), "v"(sa[11]));
      asm("v_cvt_pk_bf16_f32 %0, %1, %2" : "=v"(d0) : "v"(sa[12]), "v"(sa[13]));
      asm("v_cvt_pk_bf16_f32 %0, %1, %2" : "=v"(d1) : "v"(sa[14]), "v"(sa[15]));
      U8 A1, A2;
      A1.u[0] = a0; A1.u[1] = a1; A1.u[2] = b0; A1.u[3] = b1;   // sigma m 0..15
      A2.u[0] = c0; A2.u[1] = c1; A2.u[2] = d0; A2.u[3] = d1;   // sigma m 16..31

      __builtin_amdgcn_s_setprio(1);
      o[sub]  = MFMA32(A1.v, vf0, o[sub]);
      o[sub]  = MFMA32(A2.v, vf1, o[sub]);
      ol[sub] = MFMA32(A1.v, ones8, ol[sub]);    // row sums, same layout as o
      ol[sub] = MFMA32(A2.v, ones8, ol[sub]);
      __builtin_amdgcn_s_setprio(0);
    }
  }

  // epilogue: o and ol layout-matched -> plain elementwise divide
#pragma unroll
  for (int sub = 0; sub < 2; sub++) {
#pragma unroll
    for (int r = 0; r < 16; r++) {
      int q_local = (r & 3) + 8 * (r >> 2) + 4 * hi;
      int qa = w * 64 + sub * 32 + q_local;
      ctx[((size_t)(b << 8) + qa) * 192 + h * 32 + q5] =
          (bf16)(o[sub][r] / ol[sub][r]);
    }
  }
}

// ---------------------------------------------------------------------------
// Kernel D: out = ctx @ w_proj + b_proj.  grid 512, rt=2, W^T staged in LDS
// (proven ~25 us; zero-LDS variant is latency-bound per R4/R13).
// ---------------------------------------------------------------------------
#define SMEM_C (192 * 200 * 2)

__global__ __launch_bounds__(256) void proj_kernel(
    const bf16* __restrict__ ctx, const bf16* __restrict__ wpT,
    const float* __restrict__ b_proj, float* __restrict__ out) {
  extern __shared__ char smem[];
  bf16* wt = (bf16*)smem;   // [192 c][200 k]
  const int tid = threadIdx.x;
#pragma unroll
  for (int it = 0; it < 18; it++) {
    int idx = it * 256 + tid;
    int c = idx / 24, ch = idx % 24;
    bf16x8 v8 = *(const bf16x8*)(wpT + (size_t)c * 192 + ch * 8);
    *(bf16x8*)(wt + c * 200 + ch * 8) = v8;
  }
  __syncthreads();
  const int lane = tid & 63, w = tid >> 6;
  const int cI = lane & 15, gI = lane >> 4;
  const int row0 = blockIdx.x * 128 + w * 32;
  bf16x8 afr[2][6];
#pragma unroll
  for (int rt = 0; rt < 2; rt++) {
#pragma unroll
    for (int kk = 0; kk < 6; kk++)
      afr[rt][kk] = *(const bf16x8*)(ctx + (size_t)(row0 + rt * 16 + cI) * 192 +
                                     kk * 32 + gI * 8);
  }
#pragma unroll
  for (int ct = 0; ct < 12; ct++) {
    bf16x8 wfr[6];
#pragma unroll
    for (int kk = 0; kk < 6; kk++)
      wfr[kk] = *(const bf16x8*)(wt + (ct * 16 + cI) * 200 + kk * 32 + gI * 8);
    f32x4 bv4 = *(const f32x4*)(b_proj + ct * 16 + gI * 4);
#pragma unroll
    for (int rt = 0; rt < 2; rt++) {
      f32x4 acc = {0.f, 0.f, 0.f, 0.f};
#pragma unroll
      for (int kk = 0; kk < 6; kk++) acc = MFMA(wfr[kk], afr[rt][kk], acc);
      f32x4 res;
#pragma unroll
      for (int r = 0; r < 4; r++) res[r] = acc[r] + bv4[r];
      *(f32x4*)(out + (size_t)(row0 + rt * 16 + cI) * 192 + ct * 16 + gI * 4) = res;
    }
  }
}

// ---------------------------------------------------------------------------
extern "C" void kernel_launch(void* const* d_in, const int* in_sizes, int n_in,
                              void* d_out, int out_size, void* d_ws, size_t ws_size,
                              hipStream_t stream) {
  (void)in_sizes; (void)n_in; (void)out_size; (void)ws_size;
  const float* x      = (const float*)d_in[0];
  const float* mask   = (const float*)d_in[1];
  const float* w_qkv  = (const float*)d_in[2];
  const float* b_qkv  = (const float*)d_in[3];
  const float* w_proj = (const float*)d_in[4];
  const float* b_proj = (const float*)d_in[5];
  const float* pw0    = (const float*)d_in[6];
  const float* pb0    = (const float*)d_in[7];
  const float* g1     = (const float*)d_in[8];
  const float* be1    = (const float*)d_in[9];
  const float* w1     = (const float*)d_in[10];
  const float* b1     = (const float*)d_in[11];
  const float* g2     = (const float*)d_in[12];
  const float* be2    = (const float*)d_in[13];
  const float* w2     = (const float*)d_in[14];
  const float* b2     = (const float*)d_in[15];
  const float* g3     = (const float*)d_in[16];
  const float* be3    = (const float*)d_in[17];
  const float* w3     = (const float*)d_in[18];
  const float* b3     = (const float*)d_in[19];

  // ws layout (peak ~96.5 MB):
  //   wqT   @ 0         (221184)   bf16 [576][192]
  //   wpT   @ 221184    (73728)    bf16 [192][192]
  //   pos16 @ 294912    (190464)   f16 [6][31][64][8]  (*log2e)
  //   qw    @ 485376    (25165824) bf16 [b][h][n][32]  (pre-scaled s*log2e)
  //   kw    @ 25651200  (25165824)
  //   vwT   @ 50817024  (25165824) bf16 [b][h][32][n]
  //   ctx   @ 75982848  (25165824)
  // maskp (f16 [64][8][8][64][16] = 8,388,608 B) lives in d_out (50 MB);
  // proj_kernel fully overwrites d_out afterwards.
  char* ws = (char*)d_ws;
  bf16*  wqT    = (bf16*)(ws);
  bf16*  wpT    = (bf16*)(ws + 221184);
  _Float16* pos16 = (_Float16*)(ws + 294912);
  bf16*  qw     = (bf16*)(ws + 485376);
  bf16*  kw     = (bf16*)(ws + 25651200);
  bf16*  vwT    = (bf16*)(ws + 50817024);
  bf16*  ctx    = (bf16*)(ws + 75982848);
  _Float16* maskp = (_Float16*)d_out;
  float* outp   = (float*)d_out;

  hipFuncSetAttribute((const void*)qkv_gemm_kernel,
                      hipFuncAttributeMaxDynamicSharedMemorySize, SMEM_G);
  hipFuncSetAttribute((const void*)proj_kernel,
                      hipFuncAttributeMaxDynamicSharedMemorySize, SMEM_C);

  prep_wm_kernel<<<dim3(8768), dim3(256), 0, stream>>>(
      w_qkv, w_proj, mask, wqT, wpT, maskp);
  pos_prep_kernel<<<dim3(31, 6), dim3(256), 0, stream>>>(
      pw0, pb0, g1, be1, w1, b1, g2, be2, w2, b2, g3, be3, w3, b3, pos16);
  qkv_gemm_kernel<<<dim3(512), dim3(256), SMEM_G, stream>>>(
      x, wqT, b_qkv, qw, kw, vwT);
  attn_kernel<<<dim3(1536), dim3(256), 0, stream>>>(
      qw, kw, vwT, maskp, pos16, ctx);
  proj_kernel<<<dim3(512), dim3(256), SMEM_C, stream>>>(
      ctx, wpT, b_proj, outp);
}

// Round 15
// 119.440 us; speedup vs baseline: 1.4203x; 1.1016x over previous
//
#include <hip/hip_runtime.h>
#include <hip/hip_bf16.h>
#include <math.h>

typedef __bf16 bf16;
typedef __bf16 bf16x8 __attribute__((ext_vector_type(8)));
typedef __bf16 bf16x4 __attribute__((ext_vector_type(4)));
typedef float  f32x4  __attribute__((ext_vector_type(4)));
typedef float  f32x16 __attribute__((ext_vector_type(16)));
typedef _Float16 f16x8 __attribute__((ext_vector_type(8)));

#define MFMA(a, b, c)   __builtin_amdgcn_mfma_f32_16x16x32_bf16((a), (b), (c), 0, 0, 0)
#define MFMA32(a, b, c) __builtin_amdgcn_mfma_f32_32x32x16_bf16((a), (b), (c), 0, 0, 0)
#define LOG2E 1.4426950408889634f

union U8 { unsigned u[4]; bf16x8 v; };

// ---------------------------------------------------------------------------
// Kernel P1: weights + mask prep (all blocks uniform small work).
//   blocks 0..575   : precast w_qkv^T -> wqT, w_proj^T -> wpT (bf16)
//   blocks 576..8767: lane-permuted f16 mask table maskp (*log2e)
// ---------------------------------------------------------------------------
__global__ __launch_bounds__(256) void prep_wm_kernel(
    const float* __restrict__ w_qkv, const float* __restrict__ w_proj,
    const float* __restrict__ mask,
    bf16* __restrict__ wqT, bf16* __restrict__ wpT,
    _Float16* __restrict__ maskp) {
  const int blk = blockIdx.x;
  const int t = threadIdx.x;
  if (blk < 576) {
    int idx = blk * 256 + t;
    if (idx < 576 * 192) {
      int c = idx / 192, k = idx % 192;
      wqT[idx] = (bf16)w_qkv[k * 576 + c];
    } else {
      int i2 = idx - 576 * 192;
      int c = i2 / 192, k = i2 % 192;
      wpT[i2] = (bf16)w_proj[k * 192 + c];
    }
  } else {
    size_t e = ((size_t)(blk - 576) * 256 + t) * 2;
    int j  = (int)(e & 15);
    int L  = (int)((e >> 4) & 63);
    int mt = (int)((e >> 10) & 7);
    int qt = (int)((e >> 13) & 7);
    int s  = (int)(e >> 16);
    int q  = qt * 32 + (L & 31);
    int m  = mt * 32 + 16 * (j >> 3) + 8 * ((j >> 2) & 1) + 4 * (L >> 5) + (j & 3);
    const float* src = mask + ((size_t)s * 256 + q) * 256 + m;
    maskp[e]     = (_Float16)(src[0] * LOG2E);
    maskp[e + 1] = (_Float16)(src[1] * LOG2E);
  }
}

// ---------------------------------------------------------------------------
// Kernel P2: pos MLP + lane-permuted f16 table, fully parallel.
// grid (31 rd, 6 h).  Each block computes its own 31 MLP rows.
// ---------------------------------------------------------------------------
__global__ __launch_bounds__(256) void pos_prep_kernel(
    const float* __restrict__ pw0, const float* __restrict__ pb0,
    const float* __restrict__ g1,  const float* __restrict__ be1,
    const float* __restrict__ w1,  const float* __restrict__ b1,
    const float* __restrict__ g2,  const float* __restrict__ be2,
    const float* __restrict__ w2,  const float* __restrict__ b2,
    const float* __restrict__ g3,  const float* __restrict__ be3,
    const float* __restrict__ w3,  const float* __restrict__ b3,
    _Float16* __restrict__ pos16) {
  __shared__ float posh[31];
  const int rd = blockIdx.x, h = blockIdx.y;
  const int t = threadIdx.x;
  if (t < 31) {
    int i = rd * 31 + t;
    float bh = (float)(i / 31) - 15.0f;
    float bw = (float)(i % 31) - 15.0f;
    float xv[12];
#pragma unroll
    for (int j = 0; j < 12; j++) xv[j] = bh * pw0[j] + bw * pw0[12 + j] + pb0[j];
    const float* G[3]  = {g1, g2, g3};
    const float* BE[3] = {be1, be2, be3};
    const float* W[3]  = {w1, w2, w3};
    const float* BB[3] = {b1, b2, b3};
#pragma unroll
    for (int s = 0; s < 3; s++) {
      float m = 0.f;
#pragma unroll
      for (int j = 0; j < 12; j++) m += xv[j];
      m *= (1.0f / 12.0f);
      float v = 0.f;
#pragma unroll
      for (int j = 0; j < 12; j++) { float d = xv[j] - m; v += d * d; }
      v *= (1.0f / 12.0f);
      float inv = 1.0f / sqrtf(v + 1e-5f);
      float y[12];
#pragma unroll
      for (int j = 0; j < 12; j++) {
        float tt = (xv[j] - m) * inv * G[s][j] + BE[s][j];
        y[j] = tt > 0.f ? tt : 0.f;
      }
      int oc = (s == 2) ? 6 : 12;
      float on[12];
      for (int c = 0; c < oc; c++) {
        float acc = BB[s][c];
#pragma unroll
        for (int j = 0; j < 12; j++) acc += y[j] * W[s][j * oc + c];
        on[c] = acc;
      }
      for (int c = 0; c < 12; c++) xv[c] = (c < oc) ? on[c] : 0.f;
    }
    posh[t] = xv[h];
  }
  __syncthreads();
  for (int e = t; e < 512; e += 256) {
    int L = e >> 3, j = e & 7;
    int idx = (L & 15) - ((j & 3) + 8 * (j >> 2) + 4 * (L >> 5)) + 15;  // 0..30
    pos16[((h * 31 + rd) * 64 + L) * 8 + j] = (_Float16)(posh[idx] * LOG2E);
  }
}

// ---------------------------------------------------------------------------
// Kernel B: QKV GEMM.  grid 256, 512 thr / 8 waves x 32 rows (BM=256, rt=2).
// 16 waves/CU (was 8); W staged once per block per mat (half the staging).
// Q pre-scaled by scale*log2e.  Q,K swapped-MFMA -> [b][h][n][d];
// V normal -> vT[b][h][d][n].
// ---------------------------------------------------------------------------
#define SMEM_G (192 * 200 * 2)

__global__ __launch_bounds__(512) void qkv_gemm_kernel(
    const float* __restrict__ x, const bf16* __restrict__ wqT,
    const float* __restrict__ b_qkv, bf16* __restrict__ qw,
    bf16* __restrict__ kw, bf16* __restrict__ vwT) {
  extern __shared__ char smem[];
  bf16* wt = (bf16*)smem;   // [192 c][200 k]
  const int tid = threadIdx.x;
  const int lane = tid & 63, w = tid >> 6;          // w in 0..7
  const int cI = lane & 15, gI = lane >> 4;
  const int b = blockIdx.x;                         // 256 rows = 1 window
  const int row0 = b * 256 + w * 32;
  const float QSCALE = 0.17677669529663687f * LOG2E;

  bf16x8 afr[2][6];
#pragma unroll
  for (int rt = 0; rt < 2; rt++) {
#pragma unroll
    for (int kk = 0; kk < 6; kk++) {
      const float* p = x + (size_t)(row0 + rt * 16 + cI) * 192 + kk * 32 + gI * 8;
      float4 f0 = *(const float4*)p;
      float4 f1 = *(const float4*)(p + 4);
      bf16x8 a;
      a[0] = (bf16)f0.x; a[1] = (bf16)f0.y; a[2] = (bf16)f0.z; a[3] = (bf16)f0.w;
      a[4] = (bf16)f1.x; a[5] = (bf16)f1.y; a[6] = (bf16)f1.z; a[7] = (bf16)f1.w;
      afr[rt][kk] = a;
    }
  }

#pragma unroll
  for (int mat = 0; mat < 3; mat++) {
    __syncthreads();
#pragma unroll
    for (int it = 0; it < 9; it++) {
      int idx = it * 512 + tid;                     // 192 rows x 24 chunks
      int c = idx / 24, ch = idx % 24;
      bf16x8 v8 = *(const bf16x8*)(wqT + (size_t)(mat * 192 + c) * 192 + ch * 8);
      *(bf16x8*)(wt + c * 200 + ch * 8) = v8;
    }
    __syncthreads();
#pragma unroll
    for (int ct = 0; ct < 12; ct++) {
      bf16x8 wfr[6];
#pragma unroll
      for (int kk = 0; kk < 6; kk++)
        wfr[kk] = *(const bf16x8*)(wt + (ct * 16 + cI) * 200 + kk * 32 + gI * 8);
      if (mat < 2) {
        f32x4 bv4 = *(const f32x4*)(b_qkv + mat * 192 + ct * 16 + gI * 4);
        bf16* dst = (mat == 0) ? qw : kw;
#pragma unroll
        for (int rt = 0; rt < 2; rt++) {
          f32x4 acc = {0.f, 0.f, 0.f, 0.f};
#pragma unroll
          for (int kk = 0; kk < 6; kk++) acc = MFMA(wfr[kk], afr[rt][kk], acc);
          int n = w * 32 + rt * 16 + cI;
          int c0 = ct * 16 + gI * 4;
          int h = c0 >> 5, d0 = c0 & 31;
          bf16x4 o4;
          if (mat == 0) {
#pragma unroll
            for (int r = 0; r < 4; r++) o4[r] = (bf16)((acc[r] + bv4[r]) * QSCALE);
          } else {
#pragma unroll
            for (int r = 0; r < 4; r++) o4[r] = (bf16)(acc[r] + bv4[r]);
          }
          *(bf16x4*)(dst + ((size_t)(b * 6 + h) * 256 + n) * 32 + d0) = o4;
        }
      } else {
        float bv = b_qkv[384 + ct * 16 + cI];
        int c = ct * 16 + cI, h = c >> 5, d = c & 31;
#pragma unroll
        for (int rt = 0; rt < 2; rt++) {
          f32x4 acc = {0.f, 0.f, 0.f, 0.f};
#pragma unroll
          for (int kk = 0; kk < 6; kk++) acc = MFMA(afr[rt][kk], wfr[kk], acc);
          int n0 = w * 32 + rt * 16 + gI * 4;
          bf16x4 o4;
#pragma unroll
          for (int r = 0; r < 4; r++) o4[r] = (bf16)(acc[r] + bv);
          *(bf16x4*)(vwT + ((size_t)(b * 6 + h) * 32 + d) * 256 + n0) = o4;
        }
      }
    }
  }
}

// ---------------------------------------------------------------------------
// Kernel C: flash attention, 32x32 MFMA, zero LDS, no-max softmax.
// grid 1536 (b,h), 4 waves x 64 q rows = 2 subtiles of 32, K/V frags shared.
// Bias (f16 mask+pos, pk_add) pre-loaded into the QK MFMA C-operand.
// P = exp2(S) directly; l via ones-MFMA (layout-matched divide).
// mt loop unrolled x2: cross-iteration ILP (loads of i+1 hide exp chain of i).
// launch_bounds(256,3): VGPR cap 170 -> no spill.
// ---------------------------------------------------------------------------
__global__ __launch_bounds__(256, 3) void attn_kernel(
    const bf16* __restrict__ qw, const bf16* __restrict__ kw,
    const bf16* __restrict__ vwT, const _Float16* __restrict__ maskp,
    const _Float16* __restrict__ pos16, bf16* __restrict__ ctx) {
  const int tid = threadIdx.x;
  const int bid = blockIdx.x;
  const int s_ = bid & 63, j_ = bid >> 6;          // mask slice; XCD = bid%8 = s_%8
  const int g_ = j_ & 3, h = j_ >> 2;
  const int b = g_ * 64 + s_;

  const bf16* qb = qw  + (size_t)(b * 6 + h) * 8192;
  const bf16* kb = kw  + (size_t)(b * 6 + h) * 8192;
  const bf16* vb = vwT + (size_t)(b * 6 + h) * 8192;
  const _Float16* pg = pos16 + (size_t)h * (31 * 512);

  const int lane = tid & 63, w = tid >> 6;
  const int q5 = lane & 31, hi = lane >> 5;

  bf16x8 qf[2][2];
#pragma unroll
  for (int sub = 0; sub < 2; sub++) {
    int qa = w * 64 + sub * 32 + q5;
    qf[sub][0] = *(const bf16x8*)(qb + qa * 32 + hi * 8);
    qf[sub][1] = *(const bf16x8*)(qb + qa * 32 + 16 + hi * 8);
  }

  bf16x8 ones8;
#pragma unroll
  for (int j = 0; j < 8; j++) ones8[j] = (bf16)1.0f;

  f32x16 o[2], ol[2];
#pragma unroll
  for (int sub = 0; sub < 2; sub++) {
#pragma unroll
    for (int r = 0; r < 16; r++) { o[sub][r] = 0.f; ol[sub][r] = 0.f; }
  }

#pragma unroll 2
  for (int mt = 0; mt < 8; mt++) {
    const int m0 = mt * 32;
    // K A-frag + V B-frag (sigma-permuted): shared across both q-subtiles
    bf16x8 kf0 = *(const bf16x8*)(kb + (m0 + q5) * 32 + hi * 8);
    bf16x8 kf1 = *(const bf16x8*)(kb + (m0 + q5) * 32 + 16 + hi * 8);
    const bf16* vrow = vb + q5 * 256 + m0 + 4 * hi;
    bf16x4 v00 = *(const bf16x4*)(vrow);
    bf16x4 v01 = *(const bf16x4*)(vrow + 8);
    bf16x4 v10 = *(const bf16x4*)(vrow + 16);
    bf16x4 v11 = *(const bf16x4*)(vrow + 24);
    bf16x8 vf0, vf1;
#pragma unroll
    for (int j2 = 0; j2 < 4; j2++) {
      vf0[j2] = v00[j2]; vf0[4 + j2] = v01[j2];
      vf1[j2] = v10[j2]; vf1[4 + j2] = v11[j2];
    }

#pragma unroll
    for (int sub = 0; sub < 2; sub++) {
      const int qa = w * 64 + sub * 32 + q5;
      const int rn = qa >> 4;
      const int rd0 = rn - 2 * mt + 15;
      f16x8 plo = *(const f16x8*)(pg + ((size_t)rd0 * 64 + lane) * 8);
      f16x8 phi = *(const f16x8*)(pg + ((size_t)(rd0 - 1) * 64 + lane) * 8);
      const _Float16* mrow =
          maskp + ((((size_t)s_ * 8 + (w * 2 + sub)) * 8 + mt) * 64 + lane) * 16;
      f16x8 mk0 = *(const f16x8*)(mrow);
      f16x8 mk1 = *(const f16x8*)(mrow + 8);
      // bias = mask + pos in packed f16, then init the MFMA accumulator
      f16x8 b0v = mk0 + plo;
      f16x8 b1v = mk1 + phi;
      f32x16 sa;
#pragma unroll
      for (int r = 0; r < 8; r++)  sa[r]     = (float)b0v[r];
#pragma unroll
      for (int r = 0; r < 8; r++)  sa[8 + r] = (float)b1v[r];

      __builtin_amdgcn_s_setprio(1);
      sa = MFMA32(kf0, qf[sub][0], sa);
      sa = MFMA32(kf1, qf[sub][1], sa);
      __builtin_amdgcn_s_setprio(0);

      // P = 2^sa directly (no max machinery; division cancels scale)
#pragma unroll
      for (int r = 0; r < 16; r++) sa[r] = exp2f(sa[r]);

      unsigned a0, a1, b0, b1, c0, c1, d0, d1;
      asm("v_cvt_pk_bf16_f32 %0, %1, %2" : "=v"(a0) : "v"(sa[0]),  "v"(sa[1]));
      asm("v_cvt_pk_bf16_f32 %0, %1, %2" : "=v"(a1) : "v"(sa[2]),  "v"(sa[3]));
      asm("v_cvt_pk_bf16_f32 %0, %1, %2" : "=v"(b0) : "v"(sa[4]),  "v"(sa[5]));
      asm("v_cvt_pk_bf16_f32 %0, %1, %2" : "=v"(b1) : "v"(sa[6]),  "v"(sa[7]));
      asm("v_cvt_pk_bf16_f32 %0, %1, %2" : "=v"(c0) : "v"(sa[8]),  "v"(sa[9]));
      asm("v_cvt_pk_bf16_f32 %0, %1, %2" : "=v"(c1) : "v"(sa[10]), "v"(sa[11]));
      asm("v_cvt_pk_bf16_f32 %0, %1, %2" : "=v"(d0) : "v"(sa[12]), "v"(sa[13]));
      asm("v_cvt_pk_bf16_f32 %0, %1, %2" : "=v"(d1) : "v"(sa[14]), "v"(sa[15]));
      U8 A1, A2;
      A1.u[0] = a0; A1.u[1] = a1; A1.u[2] = b0; A1.u[3] = b1;   // sigma m 0..15
      A2.u[0] = c0; A2.u[1] = c1; A2.u[2] = d0; A2.u[3] = d1;   // sigma m 16..31

      __builtin_amdgcn_s_setprio(1);
      o[sub]  = MFMA32(A1.v, vf0, o[sub]);
      o[sub]  = MFMA32(A2.v, vf1, o[sub]);
      ol[sub] = MFMA32(A1.v, ones8, ol[sub]);    // row sums, same layout as o
      ol[sub] = MFMA32(A2.v, ones8, ol[sub]);
      __builtin_amdgcn_s_setprio(0);
    }
  }

  // epilogue: o and ol layout-matched -> plain elementwise divide
#pragma unroll
  for (int sub = 0; sub < 2; sub++) {
#pragma unroll
    for (int r = 0; r < 16; r++) {
      int q_local = (r & 3) + 8 * (r >> 2) + 4 * hi;
      int qa = w * 64 + sub * 32 + q_local;
      ctx[((size_t)(b << 8) + qa) * 192 + h * 32 + q5] =
          (bf16)(o[sub][r] / ol[sub][r]);
    }
  }
}

// ---------------------------------------------------------------------------
// Kernel D: out = ctx @ w_proj + b_proj.  grid 256, 512 thr / 8 waves x 32
// rows (BM=256, rt=2), W^T staged in LDS.  16 waves/CU (was 8).
// ---------------------------------------------------------------------------
#define SMEM_C (192 * 200 * 2)

__global__ __launch_bounds__(512) void proj_kernel(
    const bf16* __restrict__ ctx, const bf16* __restrict__ wpT,
    const float* __restrict__ b_proj, float* __restrict__ out) {
  extern __shared__ char smem[];
  bf16* wt = (bf16*)smem;   // [192 c][200 k]
  const int tid = threadIdx.x;
#pragma unroll
  for (int it = 0; it < 9; it++) {
    int idx = it * 512 + tid;
    int c = idx / 24, ch = idx % 24;
    bf16x8 v8 = *(const bf16x8*)(wpT + (size_t)c * 192 + ch * 8);
    *(bf16x8*)(wt + c * 200 + ch * 8) = v8;
  }
  __syncthreads();
  const int lane = tid & 63, w = tid >> 6;          // w in 0..7
  const int cI = lane & 15, gI = lane >> 4;
  const int row0 = blockIdx.x * 256 + w * 32;
  bf16x8 afr[2][6];
#pragma unroll
  for (int rt = 0; rt < 2; rt++) {
#pragma unroll
    for (int kk = 0; kk < 6; kk++)
      afr[rt][kk] = *(const bf16x8*)(ctx + (size_t)(row0 + rt * 16 + cI) * 192 +
                                     kk * 32 + gI * 8);
  }
#pragma unroll
  for (int ct = 0; ct < 12; ct++) {
    bf16x8 wfr[6];
#pragma unroll
    for (int kk = 0; kk < 6; kk++)
      wfr[kk] = *(const bf16x8*)(wt + (ct * 16 + cI) * 200 + kk * 32 + gI * 8);
    f32x4 bv4 = *(const f32x4*)(b_proj + ct * 16 + gI * 4);
#pragma unroll
    for (int rt = 0; rt < 2; rt++) {
      f32x4 acc = {0.f, 0.f, 0.f, 0.f};
#pragma unroll
      for (int kk = 0; kk < 6; kk++) acc = MFMA(wfr[kk], afr[rt][kk], acc);
      f32x4 res;
#pragma unroll
      for (int r = 0; r < 4; r++) res[r] = acc[r] + bv4[r];
      *(f32x4*)(out + (size_t)(row0 + rt * 16 + cI) * 192 + ct * 16 + gI * 4) = res;
    }
  }
}

// ---------------------------------------------------------------------------
extern "C" void kernel_launch(void* const* d_in, const int* in_sizes, int n_in,
                              void* d_out, int out_size, void* d_ws, size_t ws_size,
                              hipStream_t stream) {
  (void)in_sizes; (void)n_in; (void)out_size; (void)ws_size;
  const float* x      = (const float*)d_in[0];
  const float* mask   = (const float*)d_in[1];
  const float* w_qkv  = (const float*)d_in[2];
  const float* b_qkv  = (const float*)d_in[3];
  const float* w_proj = (const float*)d_in[4];
  const float* b_proj = (const float*)d_in[5];
  const float* pw0    = (const float*)d_in[6];
  const float* pb0    = (const float*)d_in[7];
  const float* g1     = (const float*)d_in[8];
  const float* be1    = (const float*)d_in[9];
  const float* w1     = (const float*)d_in[10];
  const float* b1     = (const float*)d_in[11];
  const float* g2     = (const float*)d_in[12];
  const float* be2    = (const float*)d_in[13];
  const float* w2     = (const float*)d_in[14];
  const float* b2     = (const float*)d_in[15];
  const float* g3     = (const float*)d_in[16];
  const float* be3    = (const float*)d_in[17];
  const float* w3     = (const float*)d_in[18];
  const float* b3     = (const float*)d_in[19];

  // ws layout (peak ~96.5 MB):
  //   wqT   @ 0         (221184)   bf16 [576][192]
  //   wpT   @ 221184    (73728)    bf16 [192][192]
  //   pos16 @ 294912    (190464)   f16 [6][31][64][8]  (*log2e)
  //   qw    @ 485376    (25165824) bf16 [b][h][n][32]  (pre-scaled s*log2e)
  //   kw    @ 25651200  (25165824)
  //   vwT   @ 50817024  (25165824) bf16 [b][h][32][n]
  //   ctx   @ 75982848  (25165824)
  // maskp (f16 [64][8][8][64][16] = 8,388,608 B) lives in d_out (50 MB);
  // proj_kernel fully overwrites d_out afterwards.
  char* ws = (char*)d_ws;
  bf16*  wqT    = (bf16*)(ws);
  bf16*  wpT    = (bf16*)(ws + 221184);
  _Float16* pos16 = (_Float16*)(ws + 294912);
  bf16*  qw     = (bf16*)(ws + 485376);
  bf16*  kw     = (bf16*)(ws + 25651200);
  bf16*  vwT    = (bf16*)(ws + 50817024);
  bf16*  ctx    = (bf16*)(ws + 75982848);
  _Float16* maskp = (_Float16*)d_out;
  float* outp   = (float*)d_out;

  hipFuncSetAttribute((const void*)qkv_gemm_kernel,
                      hipFuncAttributeMaxDynamicSharedMemorySize, SMEM_G);
  hipFuncSetAttribute((const void*)proj_kernel,
                      hipFuncAttributeMaxDynamicSharedMemorySize, SMEM_C);

  prep_wm_kernel<<<dim3(8768), dim3(256), 0, stream>>>(
      w_qkv, w_proj, mask, wqT, wpT, maskp);
  pos_prep_kernel<<<dim3(31, 6), dim3(256), 0, stream>>>(
      pw0, pb0, g1, be1, w1, b1, g2, be2, w2, b2, g3, be3, w3, b3, pos16);
  qkv_gemm_kernel<<<dim3(256), dim3(512), SMEM_G, stream>>>(
      x, wqT, b_qkv, qw, kw, vwT);
  attn_kernel<<<dim3(1536), dim3(256), 0, stream>>>(
      qw, kw, vwT, maskp, pos16, ctx);
  proj_kernel<<<dim3(256), dim3(512), SMEM_C, stream>>>(
      ctx, wpT, b_proj, outp);
}